// Round 2
// baseline (131.901 us; speedup 1.0000x reference)
//
#include <hip/hip_runtime.h>

#define NUM_NODES 10000
#define TSTEPS 1440
#define VCOLS 360        // 1440 / 4 float4 columns
#define NPART_MAX 500    // max partial rows (500*20 rows each)

// Stage 1: partial column-sums of noise [NUM_NODES, TSTEPS].
// Block b sums its row range into part[b*TSTEPS + c] with PLAIN stores —
// no atomics (the 720k device-scope atomics were the round-1 bottleneck:
// 500 serialized RMWs per address ~= 68 us).
// Thread vc owns one float4 column; a wave's 64 lanes read 1 KiB contiguous
// per row-step -> fully coalesced.
__global__ __launch_bounds__(384) void partial_sum_kernel(
        const float* __restrict__ noise, float* __restrict__ part, int npart) {
    int vc = threadIdx.x;
    if (vc >= VCOLS) return;
    int rows_per = (NUM_NODES + npart - 1) / npart;
    int r0 = blockIdx.x * rows_per;
    int r1 = r0 + rows_per;
    if (r1 > NUM_NODES) r1 = NUM_NODES;

    const float4* __restrict__ p = (const float4*)noise;
    float4 acc = make_float4(0.f, 0.f, 0.f, 0.f);
    #pragma unroll 4
    for (int i = r0; i < r1; ++i) {
        float4 v = p[(size_t)i * VCOLS + vc];
        acc.x += v.x; acc.y += v.y; acc.z += v.z; acc.w += v.w;
    }
    float4* __restrict__ po = (float4*)part;
    po[(size_t)blockIdx.x * VCOLS + vc] = acc;
}

// Stage 2: reduce npart partials per column + fused finalize.
// overall[t] = 0.8 * colmean_noise[t] + 0.5 + 0.3*sin(2*pi*(10/3600)*time[t])
//   (mean over nodes of sin(theta_t + i*2pi/N) is exactly 0: equally spaced
//    phases over a full circle -> sum of N-th roots of unity = 0)
// encrypted[t] = sin(0.5 * overall[t])
// d_out layout: [0,1440) = encrypted, [1440,2880) = overall.
__global__ void reduce_finalize_kernel(const float* __restrict__ time_tensor,
                                       const float* __restrict__ part,
                                       float* __restrict__ out, int npart) {
    int t = blockIdx.x * blockDim.x + threadIdx.x;
    if (t >= TSTEPS) return;
    float s = 0.0f;
    for (int j = 0; j < npart; ++j)      // coalesced: consecutive t per j
        s += part[(size_t)j * TSTEPS + t];
    const float TWO_PI = 6.2831853071795864769f;
    const float BRAINWAVE_FREQ = 10.0f / 3600.0f;
    float tm = time_tensor[t];
    float brain = 0.3f * sinf(TWO_PI * BRAINWAVE_FREQ * tm);
    float overall = 0.8f * (s * (1.0f / NUM_NODES)) + 0.5f + brain;
    out[TSTEPS + t] = overall;
    out[t] = sinf(0.5f * overall);
}

extern "C" void kernel_launch(void* const* d_in, const int* in_sizes, int n_in,
                              void* d_out, int out_size, void* d_ws, size_t ws_size,
                              hipStream_t stream) {
    const float* time_tensor = (const float*)d_in[0];   // [1440]
    const float* noise       = (const float*)d_in[1];   // [10000, 1440]
    float* out  = (float*)d_out;                        // [2880]
    float* part = (float*)d_ws;                         // npart * 1440 floats

    int npart = (int)(ws_size / (TSTEPS * sizeof(float)));
    if (npart > NPART_MAX) npart = NPART_MAX;
    if (npart < 1) npart = 1;

    partial_sum_kernel<<<npart, 384, 0, stream>>>(noise, part, npart);
    reduce_finalize_kernel<<<(TSTEPS + 255) / 256, 256, 0, stream>>>(
        time_tensor, part, out, npart);
}

// Round 3
// 20.109 us; speedup vs baseline: 6.5591x; 6.5591x over previous
//
#include <hip/hip_runtime.h>

#define NUM_NODES 10000
#define TSTEPS 1440
#define VCOLS 360        // 1440 / 4 float4 columns
#define NPART_MAX 500    // max partial rows

// Stage 1: partial column-sums of noise [NUM_NODES, TSTEPS].
// Block b sums its row range into part[b*TSTEPS + c] with plain coalesced
// stores (no atomics — round-1 showed 500 serialized RMWs/address = 68 us).
// Thread vc owns one float4 column; a wave's 64 lanes read 1 KiB contiguous
// per row-step -> fully coalesced.
__global__ __launch_bounds__(384) void partial_sum_kernel(
        const float* __restrict__ noise, float* __restrict__ part, int npart) {
    int vc = threadIdx.x;
    if (vc >= VCOLS) return;
    int rows_per = (NUM_NODES + npart - 1) / npart;
    int r0 = blockIdx.x * rows_per;
    int r1 = r0 + rows_per;
    if (r1 > NUM_NODES) r1 = NUM_NODES;

    const float4* __restrict__ p = (const float4*)noise;
    float4 acc = make_float4(0.f, 0.f, 0.f, 0.f);
    #pragma unroll 4
    for (int i = r0; i < r1; ++i) {
        float4 v = p[(size_t)i * VCOLS + vc];
        acc.x += v.x; acc.y += v.y; acc.z += v.z; acc.w += v.w;
    }
    float4* __restrict__ po = (float4*)part;
    po[(size_t)blockIdx.x * VCOLS + vc] = acc;
}

// Stage 2: ONE WAVE PER COLUMN (round-2's 1440-thread version was
// latency-bound at 0.25% occupancy, 120 us). 360 blocks x 4 waves = 1440
// waves; lane l sums j = l, l+64, ...; 6-step shuffle butterfly; lane 0
// applies the fused finalize:
// overall[t] = 0.8 * colmean_noise[t] + 0.5 + 0.3*sin(2*pi*(10/3600)*time[t])
//   (mean over nodes of sin(theta_t + i*2pi/N) is exactly 0: equally spaced
//    phases over a full circle -> sum of N-th roots of unity = 0)
// encrypted[t] = sin(0.5 * overall[t])
// d_out layout: [0,1440) = encrypted, [1440,2880) = overall.
__global__ __launch_bounds__(256) void reduce_finalize_kernel(
        const float* __restrict__ time_tensor,
        const float* __restrict__ part,
        float* __restrict__ out, int npart) {
    int wave = threadIdx.x >> 6;
    int lane = threadIdx.x & 63;
    int t = blockIdx.x * 4 + wave;
    if (t >= TSTEPS) return;

    float s = 0.0f;
    for (int j = lane; j < npart; j += 64)   // 8 independent loads, L2-resident
        s += part[(size_t)j * TSTEPS + t];
    #pragma unroll
    for (int off = 32; off > 0; off >>= 1)
        s += __shfl_down(s, off, 64);

    if (lane == 0) {
        const float TWO_PI = 6.2831853071795864769f;
        const float BRAINWAVE_FREQ = 10.0f / 3600.0f;
        float tm = time_tensor[t];
        float brain = 0.3f * sinf(TWO_PI * BRAINWAVE_FREQ * tm);
        float overall = 0.8f * (s * (1.0f / NUM_NODES)) + 0.5f + brain;
        out[TSTEPS + t] = overall;
        out[t] = sinf(0.5f * overall);
    }
}

extern "C" void kernel_launch(void* const* d_in, const int* in_sizes, int n_in,
                              void* d_out, int out_size, void* d_ws, size_t ws_size,
                              hipStream_t stream) {
    const float* time_tensor = (const float*)d_in[0];   // [1440]
    const float* noise       = (const float*)d_in[1];   // [10000, 1440]
    float* out  = (float*)d_out;                        // [2880]
    float* part = (float*)d_ws;                         // npart * 1440 floats

    int npart = (int)(ws_size / (TSTEPS * sizeof(float)));
    if (npart > NPART_MAX) npart = NPART_MAX;
    if (npart < 1) npart = 1;

    partial_sum_kernel<<<npart, 384, 0, stream>>>(noise, part, npart);
    reduce_finalize_kernel<<<(TSTEPS + 3) / 4, 256, 0, stream>>>(
        time_tensor, part, out, npart);
}